// Round 16
// baseline (99.238 us; speedup 1.0000x reference)
//
#include <hip/hip_runtime.h>
#include <hip/hip_bf16.h>

typedef short s8v __attribute__((ext_vector_type(8)));      // 8 bf16 (4 VGPRs) MFMA A/B frag
typedef float f4v __attribute__((ext_vector_type(4)));      // MFMA C/D frag
typedef unsigned u4v __attribute__((ext_vector_type(4)));   // 4 packed bf16-pairs

__device__ __forceinline__ unsigned short f2bf(float x) {  // RTNE fp32->bf16 (prep only)
  unsigned u = __builtin_bit_cast(unsigned, x);
  u += 0x7fffu + ((u >> 16) & 1u);
  return (unsigned short)(u >> 16);
}
// pack 2 fp32 -> packed bf16 pair {lo=a, hi=b}
#if __has_builtin(__builtin_amdgcn_cvt_pk_bf16_f32)
__device__ __forceinline__ unsigned pk2(float a, float b) {
  return __builtin_bit_cast(unsigned, __builtin_amdgcn_cvt_pk_bf16_f32(a, b));
}
#else
__device__ __forceinline__ unsigned pk2(float a, float b) {  // 3 VALU ops, round-away
  unsigned ua = __builtin_bit_cast(unsigned, a) + 0x8000u;
  unsigned ub = __builtin_bit_cast(unsigned, b) + 0x8000u;
  return __builtin_amdgcn_perm(ub, ua, 0x07060302u);  // {ub.hi16, ua.hi16}
}
#endif

// ---------------- prep: W1f/W2f fragment packs + latent->bf16 table ----------------
// ws layout (unsigned short): [0,8192) W1f, [8192,24576) W2f, [24576,+524288) latbf.
// W1f (8192): frag (h,ks): A[m=16h+l15][k=32ks+8q4+j]; k<13 -> W1 row k; k==13 -> b1;
//   14..15 -> 0; k>=16 -> W1 row k-3.
// W2f (16384): frag (h2,ks), K-permuted to match GEMM1-output register order:
//   k-slot 8q4+j (j<4) -> hidden 32ks+4q4+j ; (j>=4) -> hidden 32ks+16+4q4+(j-4).
// latbf: vectorized, 4 floats -> 2 packed-pair dwords per thread.
__global__ void prep_kernel(const float* __restrict__ W1, const float* __restrict__ b1,
                            const float* __restrict__ W2, const float* __restrict__ latent,
                            unsigned short* __restrict__ wsW) {
  int e = blockIdx.x * 256 + threadIdx.x;   // 608*256 = 155648 = 24576 + 131072
  if (e < 8192) {
    int frag = e >> 9, rem = e & 511, lane = rem >> 3, j = rem & 7;
    int h = frag >> 1, ks = frag & 1;
    int q4 = lane >> 4, l15 = lane & 15;
    int k = ks * 32 + q4 * 8 + j;
    int n = h * 16 + l15;
    float v;
    if (k < 13) v = W1[k * 128 + n];
    else if (k == 13) v = b1[n];
    else if (k < 16) v = 0.0f;
    else v = W1[(k - 3) * 128 + n];
    wsW[e] = f2bf(v);
  } else if (e < 24576) {
    int e2 = e - 8192;
    int frag = e2 >> 9, rem = e2 & 511, lane = rem >> 3, j = rem & 7;
    int h2 = frag >> 2, ks = frag & 3;
    int q4 = lane >> 4, l15 = lane & 15;
    int kd = (j < 4) ? (32 * ks + 4 * q4 + j) : (32 * ks + 16 + 4 * q4 + (j - 4));
    int n = h2 * 16 + l15;
    wsW[e] = f2bf(W2[kd * 128 + n]);
  } else {
    int i = e - 24576;                      // 4 floats -> 2 dwords, coalesced
    float4 v = ((const float4*)latent)[i];
    uint2 o;
    o.x = pk2(v.x, v.y);
    o.y = pk2(v.z, v.w);
    ((uint2*)(wsW + 24576))[i] = o;
  }
}

// ---------------- main fused kernel ----------------
// 256 threads = 4 waves; WG = 256 rows; wave wv owns rows [64wv,64wv+64) -- the SAME
// rows its threads phase-0 (thread t = row t). Grid 2048, ~2 WG/CU (VGPR-capped).
// BARRIER-FREE: no LDS staging at all except the 8 KB intra-wave PE buffer (same-wave
// write->read, lgkmcnt-ordered). W1f lives in 16 s8v registers; W2f is read from
// global -- with W1f removed from the stream, W2f (32 KB) exactly fits L1 and is
// shared by both resident WGs. b2/W3 direct global reads (L1-hot, 1 KB). Waves are
// pure dataflow and slip freely -- no whole-WG drain point anywhere (R6-R14's
// serializer). (256,2): tighter bounds trigger the gfx950 50/50 arch/acc split +
// scratch spill (R4/R5/R12: reported VGPR == budget/2, WRITE_SIZE 59-700 MB).
__global__ __launch_bounds__(256, 2) void lisagon_main(
    const float* __restrict__ coord, const unsigned short* __restrict__ latbf,
    const unsigned short* __restrict__ W1f, const unsigned short* __restrict__ W2f,
    const float* __restrict__ b2, const float* __restrict__ W3,
    const float* __restrict__ b3, float* __restrict__ out) {
  __shared__ __align__(16) unsigned PE[2][256][4];   // 8 KB: 2 planes x 256 rows x 16B

  const int t = threadIdx.x;
  const int lane = t & 63, wv = t >> 6;
  const int l15 = lane & 15, q4 = lane >> 4;

  // ---- preload all 16 W1f fragments into registers (L1/L2-hot) ----
  const s8v* W1fv = (const s8v*)W1f;
  s8v W1r[16];
#pragma unroll
  for (int i = 0; i < 16; i++) W1r[i] = W1fv[i * 64 + lane];

  // ---- phase 0 (lite): idx + area + PE for row t; NO latent traffic ----
  int idx;
  float area;
  {
    const int Rg = blockIdx.x * 256 + t;
    const int gq = Rg >> 1, p = Rg & 1;       // p=0 -> vx=-2 pass, p=1 -> vx=0 pass
    const float co = coord[gq];
    float c = (co + (p ? 0.0f : -0.000244140625f)) + 1e-6f;  // vx*rx exact
    c = fminf(fmaxf(c, -1.0f + 1e-6f), 1.0f - 1e-6f);
    double u = ((double)c * 8192.0 + 8191.0) * 0.5;          // exact searchsorted
    idx = (int)ceil(u);
    idx = min(max(idx, 0), 8191);
    float qc = ((float)(2 * idx + 1) - 8192.0f) * (1.0f / 8192.0f);  // exact grid[idx]
    float rel = (co - qc) * 8192.0f;
    area = fabsf(rel) + 1e-9f;
    float v[16];
    v[0] = rel;
    float f = rel;
#pragma unroll
    for (int i = 0; i < 6; i++) {
      v[1 + 2 * i] = __sinf(f);
      v[2 + 2 * i] = __cosf(f);
      f = f + f;                 // exact power-of-2 freqs
    }
    v[13] = 1.0f;                // bias-fold slot (W1f input dim 13 = b1)
    v[14] = 0.0f; v[15] = 0.0f;
    uint4 q0, q1;
    q0.x = pk2(v[0], v[1]);   q0.y = pk2(v[2], v[3]);
    q0.z = pk2(v[4], v[5]);   q0.w = pk2(v[6], v[7]);
    q1.x = pk2(v[8], v[9]);   q1.y = pk2(v[10], v[11]);
    q1.z = pk2(v[12], v[13]); q1.w = pk2(v[14], v[15]);
    ((uint4*)PE[0])[t] = q0;   // plane 0: values 0..7 of row t
    ((uint4*)PE[1])[t] = q1;   // plane 1: values 8..15
  }

  // ---- per-lane direct B-fragment assembly (intra-wave only; NO barrier) ----
  // chunk map (== old A1 chunk ks*4+q4): ks0: q4<2 -> PE plane q4; q4>=2 -> prev,
  // chunk q4&1. ks1: q4<2 -> self, chunk q4&1; q4>=2 -> next, chunk q4&1.
  const size_t bbase = (size_t)(blockIdx.x >> 9) * (8192 * 16);   // batch, WG-uniform
  const uint4* latv4 = (const uint4*)(latbf + bbase);   // row r chunk c = latv4[r*2+c]
  const int rbase = wv * 64;
  s8v Bf[2][4];
#pragma unroll
  for (int rt = 0; rt < 4; rt++) {
    int srcl = rt * 16 + l15;                // source lane (same wave) for this row
    int sidx = __shfl(idx, srcl, 64);
    int rp = max(sidx - 1, 0), rn = min(sidx + 1, 8191);
    int c = q4 & 1;
    uint4 g0 = latv4[rp * 2 + c];                        // ks0 chunk (q4>=2; dummy else)
    uint4 g1 = latv4[(q4 < 2 ? sidx : rn) * 2 + c];      // ks1 chunk
    uint4 pe = ((const uint4*)PE[c])[rbase + srcl];      // PE chunk (q4<2; dummy else)
    uint4 b0;
    b0.x = q4 < 2 ? pe.x : g0.x;  b0.y = q4 < 2 ? pe.y : g0.y;
    b0.z = q4 < 2 ? pe.z : g0.z;  b0.w = q4 < 2 ? pe.w : g0.w;
    Bf[0][rt] = __builtin_bit_cast(s8v, b0);
    Bf[1][rt] = __builtin_bit_cast(s8v, g1);
  }

  // ---- GEMM1' (h-outer): one h-tile acc live; relu+pack DIRECTLY into bbv lanes ----
  // bbv[rt][ks] is GEMM2's B-fragment for K-chunk ks (K-permuted to match W2f):
  //   lane 2h'+half holds packed pair from GEMM1 output h = 2ks+h', half in {0,1}.
  u4v bbv[4][4];
#pragma unroll
  for (int h = 0; h < 8; h++) {
    f4v a[4];
#pragma unroll
    for (int rt = 0; rt < 4; rt++) a[rt] = (f4v){0.f, 0.f, 0.f, 0.f};
#pragma unroll
    for (int ks = 0; ks < 2; ks++) {
#pragma unroll
      for (int rt = 0; rt < 4; rt++)
        a[rt] = __builtin_amdgcn_mfma_f32_16x16x32_bf16(W1r[h * 2 + ks], Bf[ks][rt],
                                                        a[rt], 0, 0, 0);
    }
#pragma unroll
    for (int rt = 0; rt < 4; rt++) {
      bbv[rt][h >> 1][2 * (h & 1)]     = pk2(fmaxf(a[rt][0], 0.f), fmaxf(a[rt][1], 0.f));
      bbv[rt][h >> 1][2 * (h & 1) + 1] = pk2(fmaxf(a[rt][2], 0.f), fmaxf(a[rt][3], 0.f));
    }
  }

  // ---- GEMM2' (h2-outer, W2f from global/L1): b2 as acc-init; consume into dot ----
  const s8v* W2fv = (const s8v*)W2f;
  float s[4] = {0.f, 0.f, 0.f, 0.f};
#pragma unroll
  for (int h2 = 0; h2 < 8; h2++) {
    f4v a2[4];
    f4v b2v = ((const f4v*)b2)[h2 * 4 + q4];   // L1-hot; elem i -> h2dim 16h2+4q4+i
#pragma unroll
    for (int rt = 0; rt < 4; rt++) a2[rt] = b2v;
#pragma unroll
    for (int ks = 0; ks < 4; ks++) {
      s8v Af = W2fv[(h2 * 4 + ks) * 64 + lane];   // global, L1-resident (32 KB total)
#pragma unroll
      for (int rt = 0; rt < 4; rt++)
        a2[rt] = __builtin_amdgcn_mfma_f32_16x16x32_bf16(
            Af, __builtin_bit_cast(s8v, bbv[rt][ks]), a2[rt], 0, 0, 0);
    }
    float4 w3v = ((const float4*)W3)[h2 * 4 + q4];   // L1-hot
#pragma unroll
    for (int rt = 0; rt < 4; rt++) {
      s[rt] += fmaxf(a2[rt][0], 0.f) * w3v.x;
      s[rt] += fmaxf(a2[rt][1], 0.f) * w3v.y;
      s[rt] += fmaxf(a2[rt][2], 0.f) * w3v.z;
      s[rt] += fmaxf(a2[rt][3], 0.f) * w3v.w;
    }
  }

  // ---- layer-3 reduce + local-ensemble combine (area via same-wave shfl) ----
  const float b3s = b3[0];
#pragma unroll
  for (int rt = 0; rt < 4; rt++) {
    float pred = s[rt];
    pred += __shfl_xor(pred, 16, 64);
    pred += __shfl_xor(pred, 32, 64);
    pred += b3s;
    float other = __shfl_xor(pred, 1, 64);   // (pass0, pass1) at adjacent l15
    float a0 = __shfl(area, rt * 16 + l15, 64);       // rows live in this wave
    float a1 = __shfl(area, rt * 16 + l15 + 1, 64);
    if (q4 == 0 && (l15 & 1) == 0) {
      int row0 = rbase + rt * 16 + l15;
      float tot = a0 + a1;
      // local_ensemble swap: pred(vx=-2)*a1/tot + pred(vx=0)*a0/tot
      out[(blockIdx.x * 256 + row0) >> 1] = pred * (a1 / tot) + other * (a0 / tot);
    }
  }
}

extern "C" void kernel_launch(void* const* d_in, const int* in_sizes, int n_in,
                              void* d_out, int out_size, void* d_ws, size_t ws_size,
                              hipStream_t stream) {
  const float* coord  = (const float*)d_in[0];
  const float* latent = (const float*)d_in[1];
  const float* W1 = (const float*)d_in[2];
  const float* b1 = (const float*)d_in[3];
  const float* W2 = (const float*)d_in[4];
  const float* b2 = (const float*)d_in[5];
  const float* W3 = (const float*)d_in[6];
  const float* b3 = (const float*)d_in[7];
  float* out = (float*)d_out;
  unsigned short* wsW = (unsigned short*)d_ws;   // W1f | W2f | latbf

  prep_kernel<<<608, 256, 0, stream>>>(W1, b1, W2, latent, wsW);
  lisagon_main<<<2048, 256, 0, stream>>>(coord, wsW + 24576, wsW, wsW + 8192,
                                         b2, W3, b3, out);
}

// Round 17
// 96.167 us; speedup vs baseline: 1.0319x; 1.0319x over previous
//
#include <hip/hip_runtime.h>
#include <hip/hip_bf16.h>

typedef short s8v __attribute__((ext_vector_type(8)));      // 8 bf16 (4 VGPRs) MFMA A/B frag
typedef float f4v __attribute__((ext_vector_type(4)));      // MFMA C/D frag
typedef unsigned u4v __attribute__((ext_vector_type(4)));   // 4 packed bf16-pairs

__device__ __forceinline__ unsigned short f2bf(float x) {  // RTNE fp32->bf16 (prep only)
  unsigned u = __builtin_bit_cast(unsigned, x);
  u += 0x7fffu + ((u >> 16) & 1u);
  return (unsigned short)(u >> 16);
}
// pack 2 fp32 -> packed bf16 pair {lo=a, hi=b}
#if __has_builtin(__builtin_amdgcn_cvt_pk_bf16_f32)
__device__ __forceinline__ unsigned pk2(float a, float b) {
  return __builtin_bit_cast(unsigned, __builtin_amdgcn_cvt_pk_bf16_f32(a, b));
}
#else
__device__ __forceinline__ unsigned pk2(float a, float b) {  // 3 VALU ops, round-away
  unsigned ua = __builtin_bit_cast(unsigned, a) + 0x8000u;
  unsigned ub = __builtin_bit_cast(unsigned, b) + 0x8000u;
  return __builtin_amdgcn_perm(ub, ua, 0x07060302u);  // {ub.hi16, ua.hi16}
}
#endif

// async global->LDS DMA, 16 B per lane; LDS dest = wave-uniform base + lane*16
__device__ __forceinline__ void g2lds16(const void* g, void* l) {
  __builtin_amdgcn_global_load_lds(
      (const __attribute__((address_space(1))) unsigned*)g,
      (__attribute__((address_space(3))) unsigned*)l, 16, 0, 0);
}

// ---------------- prep: W1f/W2f fragment packs + latent->bf16 table ----------------
// ws layout (unsigned short): [0,8192) W1f, [8192,24576) W2f, [24576,+524288) latbf.
// W1f (8192): frag (h,ks): A[m=16h+l15][k=32ks+8q4+j]; k<13 -> W1 row k; k==13 -> b1;
//   14..15 -> 0; k>=16 -> W1 row k-3.
// W2f (16384): frag (h2,ks), K-permuted to match GEMM1-output register order:
//   k-slot 8q4+j (j<4) -> hidden 32ks+4q4+j ; (j>=4) -> hidden 32ks+16+4q4+(j-4).
// latbf: vectorized, 4 floats -> 2 packed-pair dwords per thread (R16, ~1.5us faster).
__global__ void prep_kernel(const float* __restrict__ W1, const float* __restrict__ b1,
                            const float* __restrict__ W2, const float* __restrict__ latent,
                            unsigned short* __restrict__ wsW) {
  int e = blockIdx.x * 256 + threadIdx.x;   // 608*256 = 155648 = 24576 + 131072
  if (e < 8192) {
    int frag = e >> 9, rem = e & 511, lane = rem >> 3, j = rem & 7;
    int h = frag >> 1, ks = frag & 1;
    int q4 = lane >> 4, l15 = lane & 15;
    int k = ks * 32 + q4 * 8 + j;
    int n = h * 16 + l15;
    float v;
    if (k < 13) v = W1[k * 128 + n];
    else if (k == 13) v = b1[n];
    else if (k < 16) v = 0.0f;
    else v = W1[(k - 3) * 128 + n];
    wsW[e] = f2bf(v);
  } else if (e < 24576) {
    int e2 = e - 8192;
    int frag = e2 >> 9, rem = e2 & 511, lane = rem >> 3, j = rem & 7;
    int h2 = frag >> 2, ks = frag & 3;
    int q4 = lane >> 4, l15 = lane & 15;
    int kd = (j < 4) ? (32 * ks + 4 * q4 + j) : (32 * ks + 16 + 4 * q4 + (j - 4));
    int n = h2 * 16 + l15;
    wsW[e] = f2bf(W2[kd * 128 + n]);
  } else {
    int i = e - 24576;                      // 4 floats -> 2 dwords, coalesced
    float4 v = ((const float4*)latent)[i];
    uint2 o;
    o.x = pk2(v.x, v.y);
    o.y = pk2(v.z, v.w);
    ((uint2*)(wsW + 24576))[i] = o;
  }
}

// ---------------- main fused kernel (R15 structure + XCD swizzle) ----------------
// 256 threads = 4 waves; WG = 256 rows; wave wv owns rows [64wv,64wv+64) -- the SAME
// rows its threads phase-0 (thread t = row t). Grid 2048, 2 WG/CU.
// Direct B-fragment assembly (no A1 staging): frag chunk (ks,q4) of row n is a
// contiguous 16B piece of latbf (prev/self/next row, chunk q4&1) gathered per-lane,
// or a PE chunk (ks0,q4<2) from an 8 KB intra-wave LDS buffer (same-wave write->read,
// lgkmcnt-ordered, NO barrier). W2f staged to LDS by DMA; the single __syncthreads
// sits AFTER GEMM1 so the DMA gets ~3k cyc of cover and phase-0 never waits on a
// whole-WG drain. XCD swizzle: bid remap gives each XCD ONE batch (~1.3 MB L2
// working set vs 4.3 MB at round-robin) -> latent gathers are reliable L2 hits.
// (256,2): tighter bounds trigger the gfx950 50/50 arch/acc split + scratch spill
// (R4/R5/R12: reported VGPR == budget/2, WRITE_SIZE 59-700 MB).
__global__ __launch_bounds__(256, 2) void lisagon_main(
    const float* __restrict__ coord, const unsigned short* __restrict__ latbf,
    const unsigned short* __restrict__ W1f, const unsigned short* __restrict__ W2f,
    const float* __restrict__ b2, const float* __restrict__ W3,
    const float* __restrict__ b3, float* __restrict__ out) {
  __shared__ __align__(16) unsigned short W2s[16384];      // 32 KB W2 fragments
  __shared__ __align__(16) unsigned PE[2][256][4];         // 8 KB: 2 planes x 256 rows
  __shared__ __align__(16) float BW[256];                  // b2 [0,128) | W3 [128,256)

  const int t = threadIdx.x;
  const int lane = t & 63, wv = t >> 6;
  const int l15 = lane & 15, q4 = lane >> 4;
  // XCD-aware swizzle (bijective on [0,2048)): physical blocks i%8==j (one XCD under
  // round-robin) all land in batch j>>1. Speed-only heuristic (G16-safe).
  const int bid = ((blockIdx.x & 7) >> 1) * 512 + ((blockIdx.x >> 3) << 1) + (blockIdx.x & 1);

  // ---- issue W2f -> LDS DMA first (covered until the post-GEMM1 barrier) ----
#pragma unroll
  for (int it = 0; it < 8; it++) {
    int off = (it * 4 + wv) * 1024;          // bytes; wave-uniform LDS base
    g2lds16((const char*)W2f + off + lane * 16, (char*)W2s + off);
  }
  // ---- stage b2 / W3 into LDS (1 KB; visible after the barrier) ----
  if (t < 64) {
    ((float4*)BW)[t] = (t < 32) ? ((const float4*)b2)[t] : ((const float4*)W3)[t - 32];
  }
  // ---- preload all 16 W1f fragments into registers (L1/L2-hot) ----
  const s8v* W1fv = (const s8v*)W1f;
  s8v W1r[16];
#pragma unroll
  for (int i = 0; i < 16; i++) W1r[i] = W1fv[i * 64 + lane];

  // ---- phase 0 (lite): idx + area + PE for row t; NO latent traffic ----
  int idx;
  float area;
  {
    const int Rg = bid * 256 + t;
    const int gq = Rg >> 1, p = Rg & 1;       // p=0 -> vx=-2 pass, p=1 -> vx=0 pass
    const float co = coord[gq];
    float c = (co + (p ? 0.0f : -0.000244140625f)) + 1e-6f;  // vx*rx exact
    c = fminf(fmaxf(c, -1.0f + 1e-6f), 1.0f - 1e-6f);
    double u = ((double)c * 8192.0 + 8191.0) * 0.5;          // exact searchsorted
    idx = (int)ceil(u);
    idx = min(max(idx, 0), 8191);
    float qc = ((float)(2 * idx + 1) - 8192.0f) * (1.0f / 8192.0f);  // exact grid[idx]
    float rel = (co - qc) * 8192.0f;
    area = fabsf(rel) + 1e-9f;
    float v[16];
    v[0] = rel;
    float f = rel;
#pragma unroll
    for (int i = 0; i < 6; i++) {
      v[1 + 2 * i] = __sinf(f);
      v[2 + 2 * i] = __cosf(f);
      f = f + f;                 // exact power-of-2 freqs
    }
    v[13] = 1.0f;                // bias-fold slot (W1f input dim 13 = b1)
    v[14] = 0.0f; v[15] = 0.0f;
    uint4 q0, q1;
    q0.x = pk2(v[0], v[1]);   q0.y = pk2(v[2], v[3]);
    q0.z = pk2(v[4], v[5]);   q0.w = pk2(v[6], v[7]);
    q1.x = pk2(v[8], v[9]);   q1.y = pk2(v[10], v[11]);
    q1.z = pk2(v[12], v[13]); q1.w = pk2(v[14], v[15]);
    ((uint4*)PE[0])[t] = q0;   // plane 0: values 0..7 of row t
    ((uint4*)PE[1])[t] = q1;   // plane 1: values 8..15
  }

  // ---- per-lane direct B-fragment assembly (intra-wave only; NO barrier) ----
  // chunk map (== old A1 chunk ks*4+q4): ks0: q4<2 -> PE plane q4; q4>=2 -> prev,
  // chunk q4&1. ks1: q4<2 -> self, chunk q4&1; q4>=2 -> next, chunk q4&1.
  const size_t bbase = (size_t)(bid >> 9) * (8192 * 16);   // batch, WG-uniform
  const uint4* latv4 = (const uint4*)(latbf + bbase);   // row r chunk c = latv4[r*2+c]
  const int rbase = wv * 64;
  s8v Bf[2][4];
#pragma unroll
  for (int rt = 0; rt < 4; rt++) {
    int srcl = rt * 16 + l15;                // source lane (same wave) for this row
    int sidx = __shfl(idx, srcl, 64);
    int rp = max(sidx - 1, 0), rn = min(sidx + 1, 8191);
    int c = q4 & 1;
    uint4 g0 = latv4[rp * 2 + c];                        // ks0 chunk (q4>=2; dummy else)
    uint4 g1 = latv4[(q4 < 2 ? sidx : rn) * 2 + c];      // ks1 chunk
    uint4 pe = ((const uint4*)PE[c])[rbase + srcl];      // PE chunk (q4<2; dummy else)
    uint4 b0;
    b0.x = q4 < 2 ? pe.x : g0.x;  b0.y = q4 < 2 ? pe.y : g0.y;
    b0.z = q4 < 2 ? pe.z : g0.z;  b0.w = q4 < 2 ? pe.w : g0.w;
    Bf[0][rt] = __builtin_bit_cast(s8v, b0);
    Bf[1][rt] = __builtin_bit_cast(s8v, g1);
  }

  // ---- GEMM1' (h-outer): one h-tile acc live; relu+pack DIRECTLY into bbv lanes ----
  // bbv[rt][ks] is GEMM2's B-fragment for K-chunk ks (K-permuted to match W2f):
  //   lane 2h'+half holds packed pair from GEMM1 output h = 2ks+h', half in {0,1}.
  u4v bbv[4][4];
#pragma unroll
  for (int h = 0; h < 8; h++) {
    f4v a[4];
#pragma unroll
    for (int rt = 0; rt < 4; rt++) a[rt] = (f4v){0.f, 0.f, 0.f, 0.f};
#pragma unroll
    for (int ks = 0; ks < 2; ks++) {
#pragma unroll
      for (int rt = 0; rt < 4; rt++)
        a[rt] = __builtin_amdgcn_mfma_f32_16x16x32_bf16(W1r[h * 2 + ks], Bf[ks][rt],
                                                        a[rt], 0, 0, 0);
    }
#pragma unroll
    for (int rt = 0; rt < 4; rt++) {
      bbv[rt][h >> 1][2 * (h & 1)]     = pk2(fmaxf(a[rt][0], 0.f), fmaxf(a[rt][1], 0.f));
      bbv[rt][h >> 1][2 * (h & 1) + 1] = pk2(fmaxf(a[rt][2], 0.f), fmaxf(a[rt][3], 0.f));
    }
  }

  __syncthreads();   // W2s DMA + BW visibility (GEMM1 already consumed Bf)

  // ---- GEMM2' (h2-outer, weights from LDS): b2 as acc-init; consume into dot ----
  const s8v* W2sv = (const s8v*)W2s;
  float s[4] = {0.f, 0.f, 0.f, 0.f};
#pragma unroll
  for (int h2 = 0; h2 < 8; h2++) {
    f4v a2[4];
    f4v b2v = ((const f4v*)BW)[h2 * 4 + q4];   // LDS broadcast; elem i -> h2 16h2+4q4+i
#pragma unroll
    for (int rt = 0; rt < 4; rt++) a2[rt] = b2v;
#pragma unroll
    for (int ks = 0; ks < 4; ks++) {
      s8v Af = W2sv[(h2 * 4 + ks) * 64 + lane];   // ds_read_b128, conflict-free
#pragma unroll
      for (int rt = 0; rt < 4; rt++)
        a2[rt] = __builtin_amdgcn_mfma_f32_16x16x32_bf16(
            Af, __builtin_bit_cast(s8v, bbv[rt][ks]), a2[rt], 0, 0, 0);
    }
    float4 w3v = ((const float4*)(BW + 128))[h2 * 4 + q4];   // LDS broadcast
#pragma unroll
    for (int rt = 0; rt < 4; rt++) {
      s[rt] += fmaxf(a2[rt][0], 0.f) * w3v.x;
      s[rt] += fmaxf(a2[rt][1], 0.f) * w3v.y;
      s[rt] += fmaxf(a2[rt][2], 0.f) * w3v.z;
      s[rt] += fmaxf(a2[rt][3], 0.f) * w3v.w;
    }
  }

  // ---- layer-3 reduce + local-ensemble combine (area via same-wave shfl) ----
  const float b3s = b3[0];
#pragma unroll
  for (int rt = 0; rt < 4; rt++) {
    float pred = s[rt];
    pred += __shfl_xor(pred, 16, 64);
    pred += __shfl_xor(pred, 32, 64);
    pred += b3s;
    float other = __shfl_xor(pred, 1, 64);   // (pass0, pass1) at adjacent l15
    float a0 = __shfl(area, rt * 16 + l15, 64);       // rows live in this wave
    float a1 = __shfl(area, rt * 16 + l15 + 1, 64);
    if (q4 == 0 && (l15 & 1) == 0) {
      int row0 = rbase + rt * 16 + l15;
      float tot = a0 + a1;
      // local_ensemble swap: pred(vx=-2)*a1/tot + pred(vx=0)*a0/tot
      out[(bid * 256 + row0) >> 1] = pred * (a1 / tot) + other * (a0 / tot);
    }
  }
}

extern "C" void kernel_launch(void* const* d_in, const int* in_sizes, int n_in,
                              void* d_out, int out_size, void* d_ws, size_t ws_size,
                              hipStream_t stream) {
  const float* coord  = (const float*)d_in[0];
  const float* latent = (const float*)d_in[1];
  const float* W1 = (const float*)d_in[2];
  const float* b1 = (const float*)d_in[3];
  const float* W2 = (const float*)d_in[4];
  const float* b2 = (const float*)d_in[5];
  const float* W3 = (const float*)d_in[6];
  const float* b3 = (const float*)d_in[7];
  float* out = (float*)d_out;
  unsigned short* wsW = (unsigned short*)d_ws;   // W1f | W2f | latbf

  prep_kernel<<<608, 256, 0, stream>>>(W1, b1, W2, latent, wsW);
  lisagon_main<<<2048, 256, 0, stream>>>(coord, wsW + 24576, wsW, wsW + 8192,
                                         b2, W3, b3, out);
}